// Round 12
// baseline (130.878 us; speedup 1.0000x reference)
//
#include <hip/hip_runtime.h>

typedef unsigned short u16;
typedef unsigned int u32;
typedef __bf16 bf16x8 __attribute__((ext_vector_type(8)));
typedef float f32x4 __attribute__((ext_vector_type(4)));
typedef u16 u16x8 __attribute__((ext_vector_type(8)));
typedef u16 u16x4 __attribute__((ext_vector_type(4)));

// B=8, N=512, D=512, H=8, DH=64, E=32768, BIAS_DIM=8
// R12: collapse the fat prologue (ledger R8-R10: warm sum ~50us vs chain 130
// => ~80us is per-stage cold first-touch after boundary L2 WB+INV). qkv now
// consumes states/key f32 DIRECTLY via in-register cvt A-staging (R6's good
// half); B stays DMA from bf16 wT (avoids R6's in-loop B-transpose regression).
// Tiny wprep (weight transpose + bias zero) is all that precedes qkv.
// Chain: wprep -> qkv(f32 A) -> attn -> out. sb/kbin deleted (26MB unique).
// R3/R5: no in-kernel grid sync on 8-XCD MI355X (60-90us/crossing).

__device__ __forceinline__ u16 f2b(float f) {
  union { float f; u32 i; } v; v.f = f;
  u32 r = v.i + 0x7fffu + ((v.i >> 16) & 1u);
  return (u16)(r >> 16);
}

#define GLL16(gp, lp)                                                      \
  __builtin_amdgcn_global_load_lds(                                       \
      (const __attribute__((address_space(1))) u32*)(gp),                 \
      (__attribute__((address_space(3))) u32*)(lp), 16, 0, 0)

// DMA-stage a 64x64 bf16 tile (row stride 512) into linear LDS; source
// granule pre-swizzled so LDS(r,g) holds global (r, g^(r&7)).
__device__ __forceinline__ void stage64(const u16* g, u16* l, int wave, int lane) {
  int rsub = lane >> 3;
  int gs = (((lane & 7) ^ rsub) << 3);
  #pragma unroll
  for (int c = 0; c < 2; c++) {
    int ch = wave * 2 + c;
    GLL16(g + (size_t)(ch * 8 + rsub) * 512 + gs, l + ch * 512);
  }
}
__device__ __forceinline__ void stage128(const u16* g, u16* l, int wave, int lane) {
  int rsub = lane >> 3;
  int gs = (((lane & 7) ^ rsub) << 3);
  #pragma unroll
  for (int c = 0; c < 4; c++) {
    int ch = wave * 4 + c;
    GLL16(g + (size_t)(ch * 8 + rsub) * 512 + gs, l + ch * 512);
  }
}
// Swizzled read/write offset (elements) into a linear [rows][64] tile.
__device__ __forceinline__ int swz(int row, int g) {
  return row * 64 + ((g ^ (row & 7)) << 3);
}

// ---------- wprep: transpose 4 weights (Wq scaled) | zero bias ----------
__global__ __launch_bounds__(256) void wprep(
    const float* __restrict__ Wq, const float* __restrict__ Wk,
    const float* __restrict__ Wv, const float* __restrict__ Wo,
    u16* __restrict__ wbase, float* __restrict__ bias_mat) {
  __shared__ u16 t[32][33];
  int bid = blockIdx.x;
  int tid = threadIdx.x;
  if (bid < 1024) {
    int z = bid >> 8, rem = bid & 255;
    int bx = rem & 15, by = rem >> 4;
    const float* src; float sc = 1.f;
    if (z == 0)      { src = Wq; sc = 0.125f; }
    else if (z == 1) { src = Wk; }
    else if (z == 2) { src = Wv; }
    else             { src = Wo; }
    u16* dst = wbase + (size_t)z * 262144;
    int tx = tid & 31, ty = tid >> 5;
    int c0 = bx * 32, r0 = by * 32;
    #pragma unroll
    for (int i = ty; i < 32; i += 8) t[i][tx] = f2b(src[(r0 + i) * 512 + c0 + tx] * sc);
    __syncthreads();
    #pragma unroll
    for (int i = ty; i < 32; i += 8) dst[(c0 + i) * 512 + r0 + tx] = t[tx][i];
  } else {
    int i = (bid - 1024) * 256 + tid;    // 2048 blocks x 256 = 524288 float4 = 8 MB
    float4 z4 = {0.f, 0.f, 0.f, 0.f};
    ((float4*)bias_mat)[i] = z4;
  }
}

// ---------- fused QKV GEMM (f32 A in-register cvt) + edge scatter; grid (64,12) ----------
// M=4096 rows (b*512+t), N=1536 (q|k|v), K=512. A: states/key f32 direct.
// B: DMA from pre-transposed bf16 wT. v written TRANSPOSED into vtb.
// k-region blocks emit summed[(b*8+h)*512+t] = sum_a k.
__global__ __launch_bounds__(256) void qkv_gemm(const float* __restrict__ states,
                                                const float* __restrict__ key_states,
                                                const u16* __restrict__ wT,
                                                const int* __restrict__ ab,
                                                const float* __restrict__ be,
                                                const float* __restrict__ bsc,
                                                float* __restrict__ bias_m,
                                                u16* __restrict__ qb,
                                                u16* __restrict__ kbo,
                                                u16* __restrict__ vtb,
                                                float* __restrict__ summed,
                                                int n_edges) {
  __shared__ alignas(16) u16 As[2][64 * 64];
  __shared__ alignas(16) u16 Bs[2][128 * 64];
  __shared__ float ssum[4][64];
  __shared__ float tvs[8];
  int tid = threadIdx.x;
  int lane = tid & 63, wave = tid >> 6;
  int quad = lane >> 4, ln = lane & 15;
  int fb = blockIdx.y * 64 + blockIdx.x;

  // ---- edge-bias scatter preamble (bias_m zeroed by wprep dispatch) ----
  if (tid < 8) {
    const float4* bev = (const float4*)(be + tid * 64);
    const float4* bscv = (const float4*)bsc;
    float s = 0.f;
    #pragma unroll
    for (int a4 = 0; a4 < 16; a4++) {
      float4 x = bev[a4], y = bscv[a4];
      s += x.x * y.x + x.y * y.y + x.z * y.z + x.w * y.w;
    }
    tvs[tid] = s * 0.125f;
  }
  __syncthreads();
  for (int e = fb * 256 + tid; e < n_edges; e += 768 * 256) {
    int et = ab[e * 4 + 0];
    int b  = ab[e * 4 + 1];
    int qi = ab[e * 4 + 2];
    int ki = ab[e * 4 + 3];
    if (ki <= qi)   // upper-triangle edges are causally masked — never read
      atomicAdd(&bias_m[((size_t)b * 512 + qi) * 512 + ki], tvs[et]);
  }

  int row0 = blockIdx.x * 64;
  int col0 = blockIdx.y * 128;
  const float* A = (col0 < 512) ? states : key_states;
  const u16* Bb = wT + (size_t)col0 * 512;

  // A staging map: thread covers row ar (0..63), 16-col chunk aj (granules 2aj, 2aj+1)
  int ar = tid >> 2, aj = tid & 3;
  const float* apA = A + (size_t)(row0 + ar) * 512 + aj * 16;

  f32x4 acc[4][2];
  #pragma unroll
  for (int i = 0; i < 4; i++)
    #pragma unroll
    for (int j = 0; j < 2; j++) acc[i][j] = (f32x4){0.f, 0.f, 0.f, 0.f};

  float4 rA[4];
  {
    const float4* p = (const float4*)apA;
    rA[0] = p[0]; rA[1] = p[1]; rA[2] = p[2]; rA[3] = p[3];
  }
  stage128(Bb, Bs[0], wave, lane);

  int cur = 0;
  for (int k0 = 0; k0 < 512; k0 += 64) {
    __syncthreads();   // (1) drains B-DMA for buf[cur]; WAR for As/Bs[cur]
    // A: cvt + swizzled write
    {
      u16x8 q0, q1;
      q0[0]=f2b(rA[0].x); q0[1]=f2b(rA[0].y); q0[2]=f2b(rA[0].z); q0[3]=f2b(rA[0].w);
      q0[4]=f2b(rA[1].x); q0[5]=f2b(rA[1].y); q0[6]=f2b(rA[1].z); q0[7]=f2b(rA[1].w);
      q1[0]=f2b(rA[2].x); q1[1]=f2b(rA[2].y); q1[2]=f2b(rA[2].z); q1[3]=f2b(rA[2].w);
      q1[4]=f2b(rA[3].x); q1[5]=f2b(rA[3].y); q1[6]=f2b(rA[3].z); q1[7]=f2b(rA[3].w);
      *(u16x8*)&As[cur][swz(ar, 2 * aj)]     = q0;
      *(u16x8*)&As[cur][swz(ar, 2 * aj + 1)] = q1;
    }
    __syncthreads();   // (2) A-writes visible to all waves; no VMEM pending
    if (k0 < 448) {    // next-tile B-DMA + A-reg loads fly under the MFMAs
      stage128(Bb + k0 + 64, Bs[cur ^ 1], wave, lane);
      const float4* p = (const float4*)(apA + k0 + 64);
      rA[0] = p[0]; rA[1] = p[1]; rA[2] = p[2]; rA[3] = p[3];
    }
    #pragma unroll
    for (int s = 0; s < 2; s++) {
      bf16x8 af[4], bfv[2];
      #pragma unroll
      for (int i = 0; i < 4; i++)
        af[i] = *(bf16x8*)&As[cur][swz(i * 16 + ln, s * 4 + quad)];
      #pragma unroll
      for (int j = 0; j < 2; j++)
        bfv[j] = *(bf16x8*)&Bs[cur][swz(wave * 32 + j * 16 + ln, s * 4 + quad)];
      #pragma unroll
      for (int i = 0; i < 4; i++)
        #pragma unroll
        for (int j = 0; j < 2; j++)
          acc[i][j] = __builtin_amdgcn_mfma_f32_16x16x32_bf16(af[i], bfv[j], acc[i][j], 0, 0, 0);
    }
    cur ^= 1;
  }

  int region = col0 >> 9;
  int nbase = col0 & 511;
  if (region <= 1) {
    u16* Cout = region ? kbo : qb;
    #pragma unroll
    for (int i = 0; i < 4; i++)
      #pragma unroll
      for (int j = 0; j < 2; j++) {
        int mb = row0 + i * 16 + quad * 4;
        int n = nbase + wave * 32 + j * 16 + ln;
        #pragma unroll
        for (int r = 0; r < 4; r++)
          Cout[(size_t)(mb + r) * 512 + n] = f2b(acc[i][j][r]);
      }
    if (region == 1) {
      #pragma unroll
      for (int i = 0; i < 4; i++)
        #pragma unroll
        for (int r = 0; r < 4; r++) {
          float v = acc[i][0][r] + acc[i][1][r];
          v += __shfl_xor(v, 1);
          v += __shfl_xor(v, 2);
          v += __shfl_xor(v, 4);
          v += __shfl_xor(v, 8);
          if (ln == 0) ssum[wave][i * 16 + quad * 4 + r] = v;
        }
      __syncthreads();
      if (tid < 128) {
        int hl = tid >> 6, row = tid & 63;
        float s = ssum[hl * 2][row] + ssum[hl * 2 + 1][row];
        int m = row0 + row;
        int b = m >> 9, t = m & 511;
        int h = (nbase >> 6) + hl;
        summed[((size_t)(b * 8 + h)) * 512 + t] = s;
      }
    }
  } else {
    #pragma unroll
    for (int i = 0; i < 4; i++)
      #pragma unroll
      for (int j = 0; j < 2; j++) {
        int mb = row0 + i * 16 + quad * 4;
        int bb = mb >> 9, t0 = mb & 511;
        int a_abs = nbase + wave * 32 + j * 16 + ln;
        int h = a_abs >> 6, a = a_abs & 63;
        u16x4 p;
        p[0] = f2b(acc[i][j][0]); p[1] = f2b(acc[i][j][1]);
        p[2] = f2b(acc[i][j][2]); p[3] = f2b(acc[i][j][3]);
        *(u16x4*)&vtb[(((size_t)bb * 8 + h) * 64 + a) * 512 + t0] = p;
      }
  }
}

// ---------- MFMA flash attention, single-pass causal; grid 512 ----------
// Block p<256: (bh=p&63, qt=7-(p>>6)); p>=256: (bh, qt=(p-256)>>6).
// Round-robin p->CU pairs qt (8+1),(7+2),(6+3),(5+4) = 9 k-tiles per CU.
__global__ __launch_bounds__(256) void attn_mfma(const u16* __restrict__ q,
                                                 const u16* __restrict__ k,
                                                 const u16* __restrict__ vt,
                                                 const float* __restrict__ bias_mat,
                                                 const float* __restrict__ summed,
                                                 u16* __restrict__ ctx) {
  __shared__ alignas(16) u16 Qs[64 * 64];
  __shared__ alignas(16) u16 Ks[2][64 * 64];
  __shared__ alignas(16) u16 Vs[2][64 * 64];
  __shared__ alignas(16) u16 Ps[4][16 * 72];
  int tid = threadIdx.x;
  int wave = tid >> 6, lane = tid & 63;
  int quad = lane >> 4, ln = lane & 15;
  int p2 = blockIdx.x;
  int bh, qt;
  if (p2 < 256) { bh = p2 & 63; qt = 7 - (p2 >> 6); }
  else          { int q2 = p2 - 256; bh = q2 & 63; qt = q2 >> 6; }
  int b = bh >> 3, h = bh & 7;
  int q0 = qt * 64;
  int kbe = qt;

  const u16* qb_ = q + ((size_t)(b * 512 + q0)) * 512 + h * 64;
  const u16* kb_ = k + ((size_t)(b * 512)) * 512 + h * 64;
  const u16* vb_ = vt + ((size_t)bh * 64) * 512;

  stage64(qb_, Qs, wave, lane);
  stage64(kb_, Ks[0], wave, lane);
  stage64(vb_, Vs[0], wave, lane);

  float m_r[4], l_r[4];
  f32x4 o[4];
  #pragma unroll
  for (int r = 0; r < 4; r++) { m_r[r] = -3.40282347e38f; l_r[r] = 0.f; }
  #pragma unroll
  for (int nt = 0; nt < 4; nt++) o[nt] = (f32x4){0.f, 0.f, 0.f, 0.f};

  int qrow = q0 + wave * 16 + quad * 4;

  float c_skv[4], c_bias[4][4];
  #pragma unroll
  for (int nt = 0; nt < 4; nt++) {
    int t = nt * 16 + ln;
    c_skv[nt] = summed[bh * 512 + t];
    const float* bp2 = bias_mat + ((size_t)(b * 512 + qrow)) * 512 + t;
    #pragma unroll
    for (int r = 0; r < 4; r++) c_bias[nt][r] = bp2[(size_t)r * 512];
  }

  int cur = 0;
  for (int kb = 0; kb <= kbe; kb++) {
    __syncthreads();

    float n_skv[4], n_bias[4][4];
    if (kb < kbe) {
      stage64(kb_ + (size_t)(kb + 1) * 64 * 512, Ks[cur ^ 1], wave, lane);
      stage64(vb_ + (kb + 1) * 64, Vs[cur ^ 1], wave, lane);
      #pragma unroll
      for (int nt = 0; nt < 4; nt++) {
        int t = (kb + 1) * 64 + nt * 16 + ln;
        n_skv[nt] = summed[bh * 512 + t];
        const float* bp2 = bias_mat + ((size_t)(b * 512 + qrow)) * 512 + t;
        #pragma unroll
        for (int r = 0; r < 4; r++) n_bias[nt][r] = bp2[(size_t)r * 512];
      }
    }

    bf16x8 aq0 = *(bf16x8*)&Qs[swz(wave * 16 + ln, quad)];
    bf16x8 aq1 = *(bf16x8*)&Qs[swz(wave * 16 + ln, 4 + quad)];
    f32x4 s[4];
    #pragma unroll
    for (int nt = 0; nt < 4; nt++) {
      bf16x8 b0 = *(bf16x8*)&Ks[cur][swz(nt * 16 + ln, quad)];
      bf16x8 b1 = *(bf16x8*)&Ks[cur][swz(nt * 16 + ln, 4 + quad)];
      s[nt] = (f32x4){0.f, 0.f, 0.f, 0.f};
      s[nt] = __builtin_amdgcn_mfma_f32_16x16x32_bf16(aq0, b0, s[nt], 0, 0, 0);
      s[nt] = __builtin_amdgcn_mfma_f32_16x16x32_bf16(aq1, b1, s[nt], 0, 0, 0);
    }

    #pragma unroll
    for (int nt = 0; nt < 4; nt++) {
      int t = kb * 64 + nt * 16 + ln;
      #pragma unroll
      for (int r = 0; r < 4; r++) {
        float val = s[nt][r] + c_bias[nt][r] * c_skv[nt];
        s[nt][r] = (t <= qrow + r) ? val : -3.40282347e38f;
      }
    }

    float alpha[4];
    #pragma unroll
    for (int r = 0; r < 4; r++) {
      float tm = fmaxf(fmaxf(s[0][r], s[1][r]), fmaxf(s[2][r], s[3][r]));
      #pragma unroll
      for (int off = 8; off; off >>= 1) tm = fmaxf(tm, __shfl_xor(tm, off));
      float mn = fmaxf(m_r[r], tm);
      alpha[r] = __expf(m_r[r] - mn);
      m_r[r] = mn;
      float rs = 0.f;
      #pragma unroll
      for (int nt = 0; nt < 4; nt++) {
        float pp = __expf(s[nt][r] - mn);
        s[nt][r] = pp;
        rs += pp;
      }
      #pragma unroll
      for (int off = 8; off; off >>= 1) rs += __shfl_xor(rs, off);
      l_r[r] = l_r[r] * alpha[r] + rs;
    }

    #pragma unroll
    for (int nt = 0; nt < 4; nt++)
      #pragma unroll
      for (int r = 0; r < 4; r++)
        Ps[wave][(quad * 4 + r) * 72 + nt * 16 + ln] = f2b(s[nt][r]);
    #pragma unroll
    for (int nt = 0; nt < 4; nt++)
      #pragma unroll
      for (int r = 0; r < 4; r++)
        o[nt][r] *= alpha[r];

    bf16x8 ap0 = *(bf16x8*)&Ps[wave][ln * 72 + quad * 8];
    bf16x8 ap1 = *(bf16x8*)&Ps[wave][ln * 72 + 32 + quad * 8];
    #pragma unroll
    for (int nt = 0; nt < 4; nt++) {
      bf16x8 b0 = *(bf16x8*)&Vs[cur][swz(nt * 16 + ln, quad)];
      bf16x8 b1 = *(bf16x8*)&Vs[cur][swz(nt * 16 + ln, 4 + quad)];
      o[nt] = __builtin_amdgcn_mfma_f32_16x16x32_bf16(ap0, b0, o[nt], 0, 0, 0);
      o[nt] = __builtin_amdgcn_mfma_f32_16x16x32_bf16(ap1, b1, o[nt], 0, 0, 0);
    }

    if (kb < kbe) {
      #pragma unroll
      for (int nt = 0; nt < 4; nt++) {
        c_skv[nt] = n_skv[nt];
        #pragma unroll
        for (int r = 0; r < 4; r++) c_bias[nt][r] = n_bias[nt][r];
      }
    }
    cur ^= 1;
  }

  #pragma unroll
  for (int r = 0; r < 4; r++) {
    float inv = 1.f / l_r[r];
    int qr2 = qrow + r;
    u16* dst = ctx + ((size_t)(b * 512 + qr2)) * 512 + h * 64;
    #pragma unroll
    for (int nt = 0; nt < 4; nt++)
      dst[nt * 16 + ln] = f2b(o[nt][r] * inv);
  }
}

// ---------- out GEMM: 64x64 tile; grid (64,8)=512 ----------
__global__ __launch_bounds__(256) void out_gemm(const u16* __restrict__ A,
                                                const u16* __restrict__ BT,
                                                float* __restrict__ C) {
  __shared__ alignas(16) u16 As[2][64 * 64];
  __shared__ alignas(16) u16 Bs[2][64 * 64];
  int tid = threadIdx.x;
  int lane = tid & 63, wave = tid >> 6;
  int quad = lane >> 4, ln = lane & 15;
  int wr = wave >> 1, wc = wave & 1;
  int row0 = blockIdx.x * 64;
  int col0 = blockIdx.y * 64;
  const u16* Ab = A + (size_t)row0 * 512;
  const u16* Bb = BT + (size_t)col0 * 512;

  f32x4 acc[2][2];
  #pragma unroll
  for (int i = 0; i < 2; i++)
    #pragma unroll
    for (int j = 0; j < 2; j++) acc[i][j] = (f32x4){0.f, 0.f, 0.f, 0.f};

  stage64(Ab, As[0], wave, lane);
  stage64(Bb, Bs[0], wave, lane);

  int cur = 0;
  for (int k0 = 0; k0 < 512; k0 += 64) {
    __syncthreads();
    if (k0 < 448) {
      stage64(Ab + k0 + 64, As[cur ^ 1], wave, lane);
      stage64(Bb + k0 + 64, Bs[cur ^ 1], wave, lane);
    }
    #pragma unroll
    for (int s = 0; s < 2; s++) {
      bf16x8 af[2], bfv[2];
      #pragma unroll
      for (int i = 0; i < 2; i++)
        af[i] = *(bf16x8*)&As[cur][swz(wr * 32 + i * 16 + ln, s * 4 + quad)];
      #pragma unroll
      for (int j = 0; j < 2; j++)
        bfv[j] = *(bf16x8*)&Bs[cur][swz(wc * 32 + j * 16 + ln, s * 4 + quad)];
      #pragma unroll
      for (int i = 0; i < 2; i++)
        #pragma unroll
        for (int j = 0; j < 2; j++)
          acc[i][j] = __builtin_amdgcn_mfma_f32_16x16x32_bf16(af[i], bfv[j], acc[i][j], 0, 0, 0);
    }
    cur ^= 1;
  }
  #pragma unroll
  for (int i = 0; i < 2; i++)
    #pragma unroll
    for (int j = 0; j < 2; j++) {
      int mb = row0 + wr * 32 + i * 16 + quad * 4;
      int n = col0 + wc * 32 + j * 16 + ln;
      #pragma unroll
      for (int r = 0; r < 4; r++)
        C[(size_t)(mb + r) * 512 + n] = acc[i][j][r];
    }
}

extern "C" void kernel_launch(void* const* d_in, const int* in_sizes, int n_in,
                              void* d_out, int out_size, void* d_ws, size_t ws_size,
                              hipStream_t stream) {
  const float* states     = (const float*)d_in[0];
  const float* key_states = (const float*)d_in[1];
  const int*   ab         = (const int*)d_in[3];
  const float* Wq         = (const float*)d_in[4];
  const float* Wk         = (const float*)d_in[5];
  const float* Wv         = (const float*)d_in[6];
  const float* Wo         = (const float*)d_in[7];
  const float* be         = (const float*)d_in[8];
  const float* bsc        = (const float*)d_in[9];
  float* out = (float*)d_out;

  char* ws = (char*)d_ws;
  const size_t MB = 1024 * 1024;
  // Compact layout (~26 MB unique): sb/kbin deleted (qkv reads f32 inputs).
  u16* wbase    = (u16*)(ws);                 // 2 MB: wqT|wkT|wvT|woT
  u16* wot      = (u16*)(ws + 1536 * 1024);
  u16* qb       = (u16*)(ws + 2 * MB);        // 4 MB
  u16* kbo      = (u16*)(ws + 6 * MB);        // 4 MB
  u16* vtb      = (u16*)(ws + 10 * MB);       // 4 MB (b,h,a,t)
  u16* ctxb     = (u16*)(ws + 14 * MB);       // 4 MB
  float* bias_m = (float*)(ws + 18 * MB);     // 8 MB
  float* summed = (float*)(ws + 26 * MB);     // 128 KB

  int n_edges = in_sizes[3] / 4;

  wprep<<<dim3(3072), 256, 0, stream>>>(Wq, Wk, Wv, Wo, wbase, bias_m);
  qkv_gemm<<<dim3(64, 12), 256, 0, stream>>>(
      states, key_states, wbase, ab, be, bsc, bias_m, qb, kbo, vtb, summed, n_edges);
  attn_mfma<<<dim3(512), 256, 0, stream>>>(qb, kbo, vtb, bias_m, summed, ctxb);
  out_gemm<<<dim3(64, 8), 256, 0, stream>>>(ctxb, wot, out);
}